// Round 10
// baseline (450.741 us; speedup 1.0000x reference)
//
#include <hip/hip_runtime.h>
#include <hip/hip_bf16.h>

#define NEG_SLOPE 0.2f

typedef __attribute__((ext_vector_type(8))) short short8;
typedef __attribute__((ext_vector_type(4))) float f32x4;
typedef __attribute__((ext_vector_type(2))) float f32x2;

__device__ __forceinline__ float lrelu(float x) { return x >= 0.f ? x : NEG_SLOPE * x; }

// pack two fp32 -> bf16x2 (RNE), low = a, high = b
__device__ __forceinline__ unsigned pack_bf2(float a, float b) {
    unsigned ua = __float_as_uint(a), ub = __float_as_uint(b);
    ua = (ua + 0x7fffu + ((ua >> 16) & 1u)) >> 16;
    ub = (ub + 0x7fffu + ((ub >> 16) & 1u)) & 0xffff0000u;
    return ua | ub;
}
__device__ __forceinline__ float2 unpack_bf2(unsigned u) {
    return make_float2(__uint_as_float(u << 16), __uint_as_float(u & 0xffff0000u));
}
__device__ __forceinline__ f32x2 unpack_bf2v(unsigned u) {
    f32x2 r;
    r.x = __uint_as_float(u << 16);
    r.y = __uint_as_float(u & 0xffff0000u);
    return r;
}
__device__ __forceinline__ unsigned short bf16_of(float a) {
    unsigned ua = __float_as_uint(a);
    return (unsigned short)((ua + 0x7fffu + ((ua >> 16) & 1u)) >> 16);
}
// packed fp32 fma: c += a*b on both halves (1 VOP3P instr, CDNA dual-fp32)
__device__ __forceinline__ f32x2 pk_fma(f32x2 a, f32x2 b, f32x2 c) {
    asm("v_pk_fma_f32 %0, %1, %2, %0" : "+v"(c) : "v"(a), "v"(b));
    return c;
}

// ================= CSR build: two-level counting sort, all counts in LDS =================
#define NBLK 256

// Fused stage 0 (1024 threads): w1cvt (blocks [0,16)) ∥ pcount (blocks [16,16+NBLK)).
__global__ __launch_bounds__(1024) void fused0_kernel(const float* __restrict__ W1,
                                                      unsigned short* __restrict__ W1t,
                                                      const int* __restrict__ dst,
                                                      int* __restrict__ blk_cnt,
                                                      int etot, int npart, int chunk) {
    if ((int)blockIdx.x < 16) {
        int t = blockIdx.x * 1024 + threadIdx.x;  // 16384 total
        int k = t >> 6, nn = t & 63;
        W1t[(size_t)nn * 256 + k] = bf16_of(W1[t]);
    } else {
        __shared__ int cnt[800];
        int bid = blockIdx.x - 16;
        for (int c = threadIdx.x; c < npart; c += 1024) cnt[c] = 0;
        __syncthreads();
        int e0 = bid * chunk, e1 = min(etot, e0 + chunk);
        for (int e = e0 + (int)threadIdx.x; e < e1; e += 1024)
            atomicAdd(&cnt[dst[e] >> 7], 1);
        __syncthreads();
        for (int c = threadIdx.x; c < npart; c += 1024)
            blk_cnt[(size_t)bid * npart + c] = cnt[c];
    }
}

// per-partition scan over the NBLK chunk blocks (one block per partition column).
__global__ __launch_bounds__(256) void pscanA_kernel(const int* __restrict__ blk_cnt,
                                                     int* __restrict__ blk_base,
                                                     int* __restrict__ ptot, int npart) {
    __shared__ int sm[256];
    int t = threadIdx.x, c = blockIdx.x;
    int v = blk_cnt[(size_t)t * npart + c];
    sm[t] = v;
    __syncthreads();
    for (int off = 1; off < 256; off <<= 1) {
        int u = (t >= off) ? sm[t - off] : 0;
        __syncthreads();
        sm[t] += u;
        __syncthreads();
    }
    blk_base[(size_t)t * npart + c] = sm[t] - v;  // block-local exclusive
    if (t == 255) ptot[c] = sm[t];
}

// cross-partition exclusive scan of totals -> colbase[npart+1]
__global__ __launch_bounds__(1024) void pscanB_kernel(const int* __restrict__ ptot,
                                                      int* __restrict__ colbase,
                                                      int npart, int etot) {
    __shared__ int sm[1024];
    int t = threadIdx.x;
    int v = (t < npart) ? ptot[t] : 0;
    sm[t] = v;
    __syncthreads();
    for (int off = 1; off < 1024; off <<= 1) {
        int u = (t >= off) ? sm[t - off] : 0;
        __syncthreads();
        sm[t] += u;
        __syncthreads();
    }
    if (t < npart) colbase[t] = sm[t] - v;
    if (t == 0) colbase[npart] = etot;
}

// gemm1 body: R4-proven 64 rows/block, zero-LDS, MFMA.
__device__ __forceinline__ void gemm1_body(int bid, const float* __restrict__ x,
                                           const unsigned short* __restrict__ W1t,
                                           unsigned short* __restrict__ h1b, int n) {
    int tid = threadIdx.x;
    int w = tid >> 6, lane = tid & 63;
    int p = lane & 15, quad = lane >> 4;
    int r0 = bid * 64;
    int row = r0 + 16 * w + p;
    const float* xrow = x + (size_t)row * 256;
    f32x4 z = {0.f, 0.f, 0.f, 0.f};
    f32x4 acc[4] = {z, z, z, z};
#pragma unroll
    for (int kc = 0; kc < 8; ++kc) {
        int k0 = kc * 32 + quad * 8;
        float4 v0 = make_float4(0.f, 0.f, 0.f, 0.f), v1 = v0;
        if (row < n) {
            v0 = *(const float4*)(xrow + k0);
            v1 = *(const float4*)(xrow + k0 + 4);
        }
        union { uint4 u; short8 s; } a;
        a.u = make_uint4(pack_bf2(v0.x, v0.y), pack_bf2(v0.z, v0.w),
                         pack_bf2(v1.x, v1.y), pack_bf2(v1.z, v1.w));
#pragma unroll
        for (int t = 0; t < 4; ++t) {
            short8 b = *(const short8*)(W1t + (size_t)(16 * t + p) * 256 + k0);
            acc[t] = __builtin_amdgcn_mfma_f32_16x16x32_bf16(a.s, b, acc[t], 0, 0, 0);
        }
    }
#pragma unroll
    for (int t = 0; t < 4; ++t)
#pragma unroll
        for (int r = 0; r < 4; ++r) {
            int gr = r0 + 16 * w + quad * 4 + r;
            if (gr < n) h1b[(size_t)gr * 64 + 16 * t + p] = bf16_of(acc[t][r]);
        }
}

// Fused: gemm1 ∥ pscatter, INTERLEAVED — every S-th block is a pscatter block so the
// CSR work is co-resident with gemm1 for the whole kernel (no tail serialization).
__global__ __launch_bounds__(256) void fusedC_kernel(const float* __restrict__ x,
                                                     const unsigned short* __restrict__ W1t,
                                                     unsigned short* __restrict__ h1b, int n,
                                                     const int* __restrict__ src,
                                                     const int* __restrict__ dst,
                                                     const int* __restrict__ blk_base,
                                                     const int* __restrict__ colbase,
                                                     int* __restrict__ eb,
                                                     int etot, int npart, int chunk, int S) {
    int b = (int)blockIdx.x;
    int ps = b / S;
    bool isps = (b % S == 0) && (ps < NBLK);
    if (!isps) {
        int gid = b - min((b + S - 1) / S, NBLK);  // bijective onto [0, g1)
        gemm1_body(gid, x, W1t, h1b, n);
    } else {
        __shared__ int cur[800];
        for (int c = threadIdx.x; c < npart; c += 256)
            cur[c] = colbase[c] + blk_base[(size_t)ps * npart + c];
        __syncthreads();
        int e0 = ps * chunk, e1 = min(etot, e0 + chunk);
        for (int e = e0 + (int)threadIdx.x; e < e1; e += 256) {
            int d = dst[e], s = src[e];
            int pos = atomicAdd(&cur[d >> 7], 1);
            eb[pos] = (d & 127) | (s << 7);
        }
    }
}

// alpha1 body
__device__ __forceinline__ void alpha1_body(int bid, const unsigned short* __restrict__ h1b,
                                            const float* __restrict__ att_s,
                                            const float* __restrict__ att_d,
                                            float* __restrict__ as1,
                                            float* __restrict__ ad1, int n) {
    int wid = threadIdx.x >> 6, lane = threadIdx.x & 63;
    int p = lane & 31;
    int r = bid * 8 + wid * 2 + (lane >> 5);
    if (r >= n) return;
    float2 sc = *(const float2*)(att_s + 2 * p);
    float2 dc = *(const float2*)(att_d + 2 * p);
    float2 h = unpack_bf2(((const unsigned*)h1b)[(size_t)r * 32 + p]);
    float ps = h.x * sc.x + h.y * sc.y;
    float pd = h.x * dc.x + h.y * dc.y;
    ps += __shfl_xor(ps, 1); pd += __shfl_xor(pd, 1);
    ps += __shfl_xor(ps, 2); pd += __shfl_xor(pd, 2);
    if ((p & 3) == 0) {
        as1[(size_t)r * 8 + (p >> 2)] = ps;
        ad1[(size_t)r * 8 + (p >> 2)] = pd;
    }
}

// Fused: alpha1 ∥ build, INTERLEAVED — every S2-th block is a build block.
__global__ __launch_bounds__(256) void fusedD_kernel(const unsigned short* __restrict__ h1b,
                                                     const float* __restrict__ att_s,
                                                     const float* __restrict__ att_d,
                                                     float* __restrict__ as1,
                                                     float* __restrict__ ad1, int n,
                                                     const int* __restrict__ eb,
                                                     const int* __restrict__ colbase,
                                                     int* __restrict__ row_ptr,
                                                     int* __restrict__ csr_src,
                                                     int etot, int npart, int S2) {
    int b = (int)blockIdx.x;
    int bp = b / S2;
    bool isb = (b % S2 == 0) && (bp < npart);
    if (!isb) {
        int aid = b - min((b + S2 - 1) / S2, npart);  // bijective onto [0, ga)
        alpha1_body(aid, h1b, att_s, att_d, as1, ad1, n);
    } else {
        __shared__ int cnt[128];
        __shared__ int sm[128];
        __shared__ int cur[128];
        int p = bp, t = threadIdx.x;
        int lo = p << 7;
        int e0 = colbase[p], e1 = colbase[p + 1];
        if (t < 128) cnt[t] = 0;
        __syncthreads();
        for (int e = e0 + t; e < e1; e += 256)
            atomicAdd(&cnt[eb[e] & 127], 1);
        __syncthreads();
        int v = 0;
        if (t < 128) { v = cnt[t]; sm[t] = v; }
        __syncthreads();
        for (int off = 1; off < 128; off <<= 1) {
            int u = (t < 128 && t >= off) ? sm[t - off] : 0;
            __syncthreads();
            if (t < 128) sm[t] += u;
            __syncthreads();
        }
        if (t < 128) {
            int ex = e0 + sm[t] - v;
            cur[t] = ex;
            int node = lo + t;
            if (node < n) row_ptr[node] = ex;
        }
        if (p == 0 && t == 0) row_ptr[n] = etot;
        __syncthreads();
        for (int e = e0 + t; e < e1; e += 256) {
            int u = eb[e];
            int pos = atomicAdd(&cur[u & 127], 1);
            csr_src[pos] = u >> 7;
        }
    }
}

// ---------------- Layer 1 aggregation: single-pass shift-free softmax ----------------
__global__ __launch_bounds__(256) void agg1_kernel(const unsigned short* __restrict__ h1b,
                                                   const float* __restrict__ as1,
                                                   const float* __restrict__ ad1,
                                                   const float* __restrict__ b1,
                                                   const int* __restrict__ row_ptr,
                                                   const int* __restrict__ csr_src,
                                                   float* __restrict__ elu1, int n) {
    int lane = threadIdx.x & 63;
    int node = blockIdx.x * 4 + (threadIdx.x >> 6);
    if (node >= n) return;
    int start = row_ptr[node], end = row_ptr[node + 1];
    int slot = lane >> 3, hd = lane & 7;
    float adh = ad1[(size_t)node * 8 + hd];
    int q = lane >> 5, p = lane & 31, hp = p >> 2;
    const unsigned* h1u = (const unsigned*)h1b;  // row stride 32 uints (128B)
    f32x2 o = {0.f, 0.f};
    float den = 0.f;
    for (int base = start; base < end; base += 64) {
        int nloc = min(64, end - base);
        int eidx = base + lane;
        int sAll = (eidx < end) ? csr_src[eidx] : 0;  // coalesced
        int e0 = 0;
        for (; e0 + 8 <= nloc; e0 += 8) {  // full 8-edge groups, unrolled
            int s = __shfl(sAll, e0 + slot);
            float v = lrelu(as1[(size_t)s * 8 + hd] + adh);
            float w = __expf(v);
            den += w;
#pragma unroll
            for (int j = 0; j < 8; j += 2) {
                int sj = __shfl(s, (j + q) * 8);
                float wj = __shfl(w, (j + q) * 8 + hp);
                f32x2 w2 = {wj, wj};
                o = pk_fma(unpack_bf2v(h1u[(size_t)sj * 32 + p]), w2, o);
            }
        }
        if (e0 < nloc) {  // tail group: dynamic bound
            int s = __shfl(sAll, e0 + slot);
            float v = lrelu(as1[(size_t)s * 8 + hd] + adh);
            float w = (e0 + slot < nloc) ? __expf(v) : 0.f;
            den += w;
            int jmax = nloc - e0;
            for (int j = 0; j < jmax; j += 2) {
                int sj = __shfl(s, (j + q) * 8);
                float wj = __shfl(w, (j + q) * 8 + hp);
                f32x2 w2 = {wj, wj};
                o = pk_fma(unpack_bf2v(h1u[(size_t)sj * 32 + p]), w2, o);
            }
        }
    }
    // den is per (slot,hd): reduce over slot bits (3,4,5)
    den += __shfl_xor(den, 8);
    den += __shfl_xor(den, 16);
    den += __shfl_xor(den, 32);
    float inv = 1.f / __shfl(den, hp);  // lane hp holds hd==hp
    o.x += __shfl_xor(o.x, 32);
    o.y += __shfl_xor(o.y, 32);
    if (lane < 32) {
        float2 bb = *(const float2*)(b1 + 2 * p);
        float v0 = o.x * inv + bb.x, v1 = o.y * inv + bb.y;
        v0 = v0 > 0.f ? v0 : __expf(v0) - 1.f;
        v1 = v1 > 0.f ? v1 : __expf(v1) - 1.f;
        *(float2*)(elu1 + (size_t)node * 64 + 2 * p) = make_float2(v0, v1);
    }
}

// ---------------- Layer 2 GEMM: h2(bf16) = elu1 @ W2, fused alpha2 ----------------
__global__ __launch_bounds__(256) void gemm2_kernel(const float* __restrict__ elu1,
                                                    const float* __restrict__ W2,
                                                    const float* __restrict__ att_s,
                                                    const float* __restrict__ att_d,
                                                    unsigned short* __restrict__ h2b,
                                                    float* __restrict__ as2,
                                                    float* __restrict__ ad2, int n) {
    __shared__ float As[64][132];
    __shared__ float Bs[64][40];
    int tid = threadIdx.x;
    int r0 = blockIdx.x * 128;
    int cx = tid & 7, ry = tid >> 3;
    float sa[5], da[5];
#pragma unroll
    for (int j = 0; j < 5; ++j) {
        sa[j] = att_s[5 * cx + j];
        da[j] = att_d[5 * cx + j];
    }
    for (int t = tid; t < 640; t += 256) {
        int k = t / 10, cq = t % 10;
        *(float4*)&Bs[k][4 * cq] = *(const float4*)(W2 + (size_t)k * 40 + 4 * cq);
    }
    for (int t = tid; t < 2048; t += 256) {
        int row = t >> 4, kq = t & 15;
        int gr = r0 + row;
        float4 av = make_float4(0.f, 0.f, 0.f, 0.f);
        if (gr < n) av = *(const float4*)(elu1 + (size_t)gr * 64 + 4 * kq);
        As[4 * kq + 0][row] = av.x;
        As[4 * kq + 1][row] = av.y;
        As[4 * kq + 2][row] = av.z;
        As[4 * kq + 3][row] = av.w;
    }
    __syncthreads();
    float acc[4][5] = {{0.f}};
#pragma unroll 8
    for (int k = 0; k < 64; ++k) {
        float4 a = *(const float4*)&As[k][4 * ry];
        float ar[4] = {a.x, a.y, a.z, a.w};
        float br[5];
#pragma unroll
        for (int j = 0; j < 5; ++j) br[j] = Bs[k][5 * cx + j];
#pragma unroll
        for (int i = 0; i < 4; ++i)
#pragma unroll
            for (int j = 0; j < 5; ++j) acc[i][j] = fmaf(ar[i], br[j], acc[i][j]);
    }
#pragma unroll
    for (int i = 0; i < 4; ++i) {
        int gr = r0 + 4 * ry + i;
        float ps = 0.f, pd = 0.f;
#pragma unroll
        for (int j = 0; j < 5; ++j) {
            ps = fmaf(acc[i][j], sa[j], ps);
            pd = fmaf(acc[i][j], da[j], pd);
        }
        ps += __shfl_xor(ps, 1); pd += __shfl_xor(pd, 1);
        ps += __shfl_xor(ps, 2); pd += __shfl_xor(pd, 2);
        ps += __shfl_xor(ps, 4); pd += __shfl_xor(pd, 4);
        if (gr < n) {
#pragma unroll
            for (int j = 0; j < 5; ++j) h2b[(size_t)gr * 40 + 5 * cx + j] = bf16_of(acc[i][j]);
            if (cx == 0) {
                as2[gr] = ps;
                ad2[gr] = pd;
            }
        }
    }
}

// ---------------- Layer 2 aggregation (single-pass) + bias + log_softmax ----------------
__global__ __launch_bounds__(256) void agg2_kernel(const unsigned short* __restrict__ h2b,
                                                   const float* __restrict__ as2,
                                                   const float* __restrict__ ad2,
                                                   const float* __restrict__ b2,
                                                   const int* __restrict__ row_ptr,
                                                   const int* __restrict__ csr_src,
                                                   float* __restrict__ out, int n) {
    int lane = threadIdx.x & 63;
    int node = blockIdx.x * 4 + (threadIdx.x >> 6);
    if (node >= n) return;
    int start = row_ptr[node], end = row_ptr[node + 1];
    float adn = ad2[node];

    int q = lane >> 5, p = lane & 31;
    int pc = min(p, 19);
    const unsigned* h2u = (const unsigned*)h2b;  // row stride 20 uints (80B)
    f32x2 o = {0.f, 0.f};
    float den = 0.f;
    for (int base = start; base < end; base += 64) {
        int nloc = min(64, end - base);
        int eidx = base + lane;
        bool valid = eidx < end;
        int sAll = valid ? csr_src[eidx] : 0;
        float v = lrelu(as2[sAll] + adn);
        float w = valid ? __expf(v) : 0.f;
        den += w;
        int g = 0;
        for (; g + 8 <= nloc; g += 8) {
#pragma unroll
            for (int j = 0; j < 8; j += 2) {
                int idx = g + j + q;
                int sj = __shfl(sAll, idx);
                float wj = __shfl(w, idx);
                f32x2 w2 = {wj, wj};
                o = pk_fma(unpack_bf2v(h2u[(size_t)sj * 20 + pc]), w2, o);
            }
        }
        if (g < nloc) {
            int jmax = nloc - g;
            for (int j = 0; j < jmax; j += 2) {
                int idx = g + j + q;
                int sj = __shfl(sAll, idx);
                float wj = __shfl(w, idx);
                f32x2 w2 = {wj, wj};
                o = pk_fma(unpack_bf2v(h2u[(size_t)sj * 20 + pc]), w2, o);
            }
        }
    }
#pragma unroll
    for (int off = 1; off < 64; off <<= 1) den += __shfl_xor(den, off);
    float inv = 1.f / den;
    o.x += __shfl_xor(o.x, 32);
    o.y += __shfl_xor(o.y, 32);
    bool act = (lane < 32) && (p < 20);
    float v0 = -1e30f, v1 = -1e30f;
    if (act) {
        float2 bb = *(const float2*)(b2 + 2 * p);
        v0 = o.x * inv + bb.x;
        v1 = o.y * inv + bb.y;
    }
    float vm = fmaxf(v0, v1);
#pragma unroll
    for (int off = 1; off < 64; off <<= 1) vm = fmaxf(vm, __shfl_xor(vm, off));
    float ex = act ? (__expf(v0 - vm) + __expf(v1 - vm)) : 0.f;
#pragma unroll
    for (int off = 1; off < 64; off <<= 1) ex += __shfl_xor(ex, off);
    if (act) {
        float lg = __logf(ex);
        *(float2*)(out + (size_t)node * 40 + 2 * p) = make_float2(v0 - vm - lg, v1 - vm - lg);
    }
}

// ---------------- launch ----------------
extern "C" void kernel_launch(void* const* d_in, const int* in_sizes, int n_in,
                              void* d_out, int out_size, void* d_ws, size_t ws_size,
                              hipStream_t stream) {
    const float* x        = (const float*)d_in[0];
    const float* W1       = (const float*)d_in[1];
    const float* att_src1 = (const float*)d_in[2];
    const float* att_dst1 = (const float*)d_in[3];
    const float* b1       = (const float*)d_in[4];
    const float* W2       = (const float*)d_in[5];
    const float* att_src2 = (const float*)d_in[6];
    const float* att_dst2 = (const float*)d_in[7];
    const float* b2       = (const float*)d_in[8];
    const int*   ei       = (const int*)d_in[9];

    int n    = in_sizes[0] / 256;   // 100000
    int etot = in_sizes[9] / 2;     // 1700000
    const int* srcp = ei;
    const int* dstp = ei + etot;

    int npart = (n + 127) >> 7;           // 782
    int chunk = (etot + NBLK - 1) / NBLK; // ~6641

    char* ws = (char*)d_ws;
    size_t off = 0;
    unsigned short* h1b = (unsigned short*)(ws + off); off += (size_t)n * 64 * 2;
    unsigned short* h2b = (unsigned short*)(ws + off); off += (size_t)n * 40 * 2;
    unsigned short* W1t = (unsigned short*)(ws + off); off += (size_t)64 * 256 * 2;
    float* elu1 = (float*)(ws + off); off += (size_t)n * 64 * 4;
    float* as1  = (float*)(ws + off); off += (size_t)n * 8 * 4;
    float* ad1  = (float*)(ws + off); off += (size_t)n * 8 * 4;
    float* as2  = (float*)(ws + off); off += (size_t)n * 4;
    float* ad2  = (float*)(ws + off); off += (size_t)n * 4;
    int* row_ptr = (int*)(ws + off); off += (size_t)(n + 64) * 4;
    int* csr_src = (int*)(ws + off); off += (size_t)etot * 4;
    int* blk_cnt = (int*)(ws + off); off += (size_t)NBLK * npart * 4;
    int* blk_base= (int*)(ws + off); off += (size_t)NBLK * npart * 4;
    int* ptot    = (int*)(ws + off); off += (size_t)npart * 4;
    int* colbase = (int*)(ws + off); off += (size_t)(npart + 1) * 4;
    float* outp = (float*)d_out;

    // packed bucket list aliases elu1 (etot*4 = 6.8MB <= n*64*4 = 25.6MB);
    // elu1 is only written by agg1, after build (fusedD) completes (stream-ordered).
    int* eb = (int*)elu1;

    int g1 = (n + 63) / 64;      // 1563 gemm1 blocks (64 rows each)
    int ga = (n + 7) / 8;        // 12500 alpha1 blocks
    int nb4 = (n + 3) / 4;

    int totC = g1 + NBLK;
    int S = totC / NBLK;         // 7: pscatter block every S-th slot
    int totD = ga + npart;
    int S2 = totD / npart;       // 16: build block every S2-th slot

    fused0_kernel<<<16 + NBLK, 1024, 0, stream>>>(W1, W1t, dstp, blk_cnt, etot, npart, chunk);
    pscanA_kernel<<<npart, 256, 0, stream>>>(blk_cnt, blk_base, ptot, npart);
    pscanB_kernel<<<1, 1024, 0, stream>>>(ptot, colbase, npart, etot);
    fusedC_kernel<<<totC, 256, 0, stream>>>(x, W1t, h1b, n, srcp, dstp, blk_base, colbase,
                                            eb, etot, npart, chunk, S);
    fusedD_kernel<<<totD, 256, 0, stream>>>(h1b, att_src1, att_dst1, as1, ad1, n,
                                            eb, colbase, row_ptr, csr_src, etot, npart, S2);
    agg1_kernel<<<nb4, 256, 0, stream>>>(h1b, as1, ad1, b1, row_ptr, csr_src, elu1, n);
    gemm2_kernel<<<(n + 127) / 128, 256, 0, stream>>>(elu1, W2, att_src2, att_dst2, h2b, as2, ad2, n);
    agg2_kernel<<<nb4, 256, 0, stream>>>(h2b, as2, ad2, b2, row_ptr, csr_src, outp, n);
}

// Round 11
// 385.268 us; speedup vs baseline: 1.1699x; 1.1699x over previous
//
#include <hip/hip_runtime.h>
#include <hip/hip_bf16.h>

#define NEG_SLOPE 0.2f

typedef __attribute__((ext_vector_type(8))) short short8;
typedef __attribute__((ext_vector_type(4))) float f32x4;
typedef __attribute__((ext_vector_type(2))) float f32x2;

__device__ __forceinline__ float lrelu(float x) { return x >= 0.f ? x : NEG_SLOPE * x; }

// pack two fp32 -> bf16x2 (RNE), low = a, high = b
__device__ __forceinline__ unsigned pack_bf2(float a, float b) {
    unsigned ua = __float_as_uint(a), ub = __float_as_uint(b);
    ua = (ua + 0x7fffu + ((ua >> 16) & 1u)) >> 16;
    ub = (ub + 0x7fffu + ((ub >> 16) & 1u)) & 0xffff0000u;
    return ua | ub;
}
__device__ __forceinline__ float2 unpack_bf2(unsigned u) {
    return make_float2(__uint_as_float(u << 16), __uint_as_float(u & 0xffff0000u));
}
__device__ __forceinline__ f32x2 unpack_bf2v(unsigned u) {
    f32x2 r;
    r.x = __uint_as_float(u << 16);
    r.y = __uint_as_float(u & 0xffff0000u);
    return r;
}
__device__ __forceinline__ unsigned short bf16_of(float a) {
    unsigned ua = __float_as_uint(a);
    return (unsigned short)((ua + 0x7fffu + ((ua >> 16) & 1u)) >> 16);
}
// packed fp32 fma: c += a*b on both halves (1 VOP3P instr, CDNA dual-fp32)
__device__ __forceinline__ f32x2 pk_fma(f32x2 a, f32x2 b, f32x2 c) {
    asm("v_pk_fma_f32 %0, %1, %2, %0" : "+v"(c) : "v"(a), "v"(b));
    return c;
}

// ================= CSR build: two-level counting sort, all counts in LDS =================
#define NBLK 256

// gemm1 body (R4-proven 64 rows/block, zero-LDS) + fused alpha epilogue:
// as1/ad1 computed from the fp32 accumulators (lane (p,quad) holds rows quad*4+r,
// cols 16t+p; head = 2t+(p>>3), c = p&7 -> reduce over lane bits 0..2).
__device__ __forceinline__ void gemm1_body(int bid, const float* __restrict__ x,
                                           const unsigned short* __restrict__ W1t,
                                           const float* __restrict__ att_s,
                                           const float* __restrict__ att_d,
                                           unsigned short* __restrict__ h1b,
                                           float* __restrict__ as1,
                                           float* __restrict__ ad1, int n) {
    int tid = threadIdx.x;
    int w = tid >> 6, lane = tid & 63;
    int p = lane & 15, quad = lane >> 4;
    int ph3 = p >> 3, pc = p & 7;
    // per-lane attention coefficients: col 16t+p -> head 2t+ph3, channel pc
    float sa[4], da[4];
#pragma unroll
    for (int t = 0; t < 4; ++t) {
        sa[t] = att_s[(2 * t + ph3) * 8 + pc];
        da[t] = att_d[(2 * t + ph3) * 8 + pc];
    }
    int r0 = bid * 64;
    int row = r0 + 16 * w + p;
    const float* xrow = x + (size_t)row * 256;
    f32x4 z = {0.f, 0.f, 0.f, 0.f};
    f32x4 acc[4] = {z, z, z, z};
#pragma unroll
    for (int kc = 0; kc < 8; ++kc) {
        int k0 = kc * 32 + quad * 8;
        float4 v0 = make_float4(0.f, 0.f, 0.f, 0.f), v1 = v0;
        if (row < n) {
            v0 = *(const float4*)(xrow + k0);
            v1 = *(const float4*)(xrow + k0 + 4);
        }
        union { uint4 u; short8 s; } a;
        a.u = make_uint4(pack_bf2(v0.x, v0.y), pack_bf2(v0.z, v0.w),
                         pack_bf2(v1.x, v1.y), pack_bf2(v1.z, v1.w));
#pragma unroll
        for (int t = 0; t < 4; ++t) {
            short8 b = *(const short8*)(W1t + (size_t)(16 * t + p) * 256 + k0);
            acc[t] = __builtin_amdgcn_mfma_f32_16x16x32_bf16(a.s, b, acc[t], 0, 0, 0);
        }
    }
#pragma unroll
    for (int r = 0; r < 4; ++r) {
        int gr = r0 + 16 * w + quad * 4 + r;
        // h1 store (bf16)
#pragma unroll
        for (int t = 0; t < 4; ++t)
            if (gr < n) h1b[(size_t)gr * 64 + 16 * t + p] = bf16_of(acc[t][r]);
        // alpha epilogue: reduce per-t partials over channel lanes (bits 0..2)
        float psv[4], pdv[4];
#pragma unroll
        for (int t = 0; t < 4; ++t) {
            float vs = acc[t][r] * sa[t];
            float vd = acc[t][r] * da[t];
            vs += __shfl_xor(vs, 1); vd += __shfl_xor(vd, 1);
            vs += __shfl_xor(vs, 2); vd += __shfl_xor(vd, 2);
            vs += __shfl_xor(vs, 4); vd += __shfl_xor(vd, 4);
            psv[t] = vs; pdv[t] = vd;
        }
        if (pc == 0 && gr < n) {
#pragma unroll
            for (int t = 0; t < 4; ++t) {
                as1[(size_t)gr * 8 + 2 * t + ph3] = psv[t];
                ad1[(size_t)gr * 8 + 2 * t + ph3] = pdv[t];
            }
        }
    }
}

// Fused: gemm1+alpha (blocks [0,g1), first — R4-proven order) ∥ pcount (tail blocks).
__global__ __launch_bounds__(256) void fusedA_kernel(const float* __restrict__ x,
                                                     const unsigned short* __restrict__ W1t,
                                                     const float* __restrict__ att_s,
                                                     const float* __restrict__ att_d,
                                                     unsigned short* __restrict__ h1b,
                                                     float* __restrict__ as1,
                                                     float* __restrict__ ad1, int n,
                                                     const int* __restrict__ dst,
                                                     int* __restrict__ blk_cnt,
                                                     int etot, int npart, int chunk, int g1) {
    if ((int)blockIdx.x < g1) {
        gemm1_body(blockIdx.x, x, W1t, att_s, att_d, h1b, as1, ad1, n);
    } else {
        __shared__ int cnt[800];
        int bid = blockIdx.x - g1;
        for (int c = threadIdx.x; c < npart; c += 256) cnt[c] = 0;
        __syncthreads();
        int e0 = bid * chunk, e1 = min(etot, e0 + chunk);
        for (int e = e0 + (int)threadIdx.x; e < e1; e += 256)
            atomicAdd(&cnt[dst[e] >> 7], 1);
        __syncthreads();
        for (int c = threadIdx.x; c < npart; c += 256)
            blk_cnt[(size_t)bid * npart + c] = cnt[c];
    }
}

// per-partition scan over the NBLK chunk blocks (one block per partition column).
__global__ __launch_bounds__(256) void pscanA_kernel(const int* __restrict__ blk_cnt,
                                                     int* __restrict__ blk_base,
                                                     int* __restrict__ ptot, int npart) {
    __shared__ int sm[256];
    int t = threadIdx.x, c = blockIdx.x;
    int v = blk_cnt[(size_t)t * npart + c];
    sm[t] = v;
    __syncthreads();
    for (int off = 1; off < 256; off <<= 1) {
        int u = (t >= off) ? sm[t - off] : 0;
        __syncthreads();
        sm[t] += u;
        __syncthreads();
    }
    blk_base[(size_t)t * npart + c] = sm[t] - v;  // block-local exclusive
    if (t == 255) ptot[c] = sm[t];
}

// cross-partition exclusive scan of totals -> colbase[npart+1]
__global__ __launch_bounds__(1024) void pscanB_kernel(const int* __restrict__ ptot,
                                                      int* __restrict__ colbase,
                                                      int npart, int etot) {
    __shared__ int sm[1024];
    int t = threadIdx.x;
    int v = (t < npart) ? ptot[t] : 0;
    sm[t] = v;
    __syncthreads();
    for (int off = 1; off < 1024; off <<= 1) {
        int u = (t >= off) ? sm[t - off] : 0;
        __syncthreads();
        sm[t] += u;
        __syncthreads();
    }
    if (t < npart) colbase[t] = sm[t] - v;
    if (t == 0) colbase[npart] = etot;
}

// bucket scatter into partition-sorted packed (d&127 | src<<7) list. LDS cursors.
__global__ __launch_bounds__(256) void pscatter_kernel(const int* __restrict__ src,
                                                       const int* __restrict__ dst,
                                                       const int* __restrict__ blk_base,
                                                       const int* __restrict__ colbase,
                                                       int* __restrict__ eb,
                                                       int etot, int npart, int chunk) {
    __shared__ int cur[800];
    for (int c = threadIdx.x; c < npart; c += 256)
        cur[c] = colbase[c] + blk_base[(size_t)blockIdx.x * npart + c];
    __syncthreads();
    int e0 = blockIdx.x * chunk, e1 = min(etot, e0 + chunk);
    for (int e = e0 + (int)threadIdx.x; e < e1; e += 256) {
        int d = dst[e], s = src[e];
        int pos = atomicAdd(&cur[d >> 7], 1);
        eb[pos] = (d & 127) | (s << 7);
    }
}

// per-partition CSR finalize — LDS histogram + scan + rank cursors
__global__ __launch_bounds__(256) void build_kernel(const int* __restrict__ eb,
                                                    const int* __restrict__ colbase,
                                                    int* __restrict__ row_ptr,
                                                    int* __restrict__ csr_src,
                                                    int n, int etot) {
    __shared__ int cnt[128];
    __shared__ int sm[128];
    __shared__ int cur[128];
    int p = blockIdx.x, t = threadIdx.x;
    int lo = p << 7;
    int e0 = colbase[p], e1 = colbase[p + 1];
    if (t < 128) cnt[t] = 0;
    __syncthreads();
    for (int e = e0 + t; e < e1; e += 256)
        atomicAdd(&cnt[eb[e] & 127], 1);
    __syncthreads();
    int v = 0;
    if (t < 128) { v = cnt[t]; sm[t] = v; }
    __syncthreads();
    for (int off = 1; off < 128; off <<= 1) {
        int u = (t < 128 && t >= off) ? sm[t - off] : 0;
        __syncthreads();
        if (t < 128) sm[t] += u;
        __syncthreads();
    }
    if (t < 128) {
        int ex = e0 + sm[t] - v;
        cur[t] = ex;
        int node = lo + t;
        if (node < n) row_ptr[node] = ex;
    }
    if (p == 0 && t == 0) row_ptr[n] = etot;
    __syncthreads();
    for (int e = e0 + t; e < e1; e += 256) {
        int u = eb[e];
        int pos = atomicAdd(&cur[u & 127], 1);
        csr_src[pos] = u >> 7;
    }
}

// ---------------- W1 pre-convert: fp32 [256][64] -> bf16 transposed [64][256] ----------------
__global__ __launch_bounds__(256) void w1cvt_kernel(const float* __restrict__ W1,
                                                    unsigned short* __restrict__ W1t) {
    int t = blockIdx.x * 256 + threadIdx.x;  // 16384 total
    int k = t >> 6, nn = t & 63;
    W1t[(size_t)nn * 256 + k] = bf16_of(W1[t]);
}

// ---------------- Layer 1 aggregation: single-pass shift-free softmax ----------------
__global__ __launch_bounds__(256) void agg1_kernel(const unsigned short* __restrict__ h1b,
                                                   const float* __restrict__ as1,
                                                   const float* __restrict__ ad1,
                                                   const float* __restrict__ b1,
                                                   const int* __restrict__ row_ptr,
                                                   const int* __restrict__ csr_src,
                                                   float* __restrict__ elu1, int n) {
    int lane = threadIdx.x & 63;
    int node = blockIdx.x * 4 + (threadIdx.x >> 6);
    if (node >= n) return;
    int start = row_ptr[node], end = row_ptr[node + 1];
    int slot = lane >> 3, hd = lane & 7;
    float adh = ad1[(size_t)node * 8 + hd];
    int q = lane >> 5, p = lane & 31, hp = p >> 2;
    const unsigned* h1u = (const unsigned*)h1b;  // row stride 32 uints (128B)
    f32x2 o = {0.f, 0.f};
    float den = 0.f;
    for (int base = start; base < end; base += 64) {
        int nloc = min(64, end - base);
        int eidx = base + lane;
        int sAll = (eidx < end) ? csr_src[eidx] : 0;  // coalesced
        int e0 = 0;
        for (; e0 + 8 <= nloc; e0 += 8) {  // full 8-edge groups, unrolled
            int s = __shfl(sAll, e0 + slot);
            float v = lrelu(as1[(size_t)s * 8 + hd] + adh);
            float w = __expf(v);
            den += w;
#pragma unroll
            for (int j = 0; j < 8; j += 2) {
                int sj = __shfl(s, (j + q) * 8);
                float wj = __shfl(w, (j + q) * 8 + hp);
                f32x2 w2 = {wj, wj};
                o = pk_fma(unpack_bf2v(h1u[(size_t)sj * 32 + p]), w2, o);
            }
        }
        if (e0 < nloc) {  // tail group: dynamic bound
            int s = __shfl(sAll, e0 + slot);
            float v = lrelu(as1[(size_t)s * 8 + hd] + adh);
            float w = (e0 + slot < nloc) ? __expf(v) : 0.f;
            den += w;
            int jmax = nloc - e0;
            for (int j = 0; j < jmax; j += 2) {
                int sj = __shfl(s, (j + q) * 8);
                float wj = __shfl(w, (j + q) * 8 + hp);
                f32x2 w2 = {wj, wj};
                o = pk_fma(unpack_bf2v(h1u[(size_t)sj * 32 + p]), w2, o);
            }
        }
    }
    // den is per (slot,hd): reduce over slot bits (3,4,5)
    den += __shfl_xor(den, 8);
    den += __shfl_xor(den, 16);
    den += __shfl_xor(den, 32);
    float inv = 1.f / __shfl(den, hp);  // lane hp holds hd==hp
    o.x += __shfl_xor(o.x, 32);
    o.y += __shfl_xor(o.y, 32);
    if (lane < 32) {
        float2 bb = *(const float2*)(b1 + 2 * p);
        float v0 = o.x * inv + bb.x, v1 = o.y * inv + bb.y;
        v0 = v0 > 0.f ? v0 : __expf(v0) - 1.f;
        v1 = v1 > 0.f ? v1 : __expf(v1) - 1.f;
        *(float2*)(elu1 + (size_t)node * 64 + 2 * p) = make_float2(v0, v1);
    }
}

// ---------------- Layer 2 GEMM: h2(bf16) = elu1 @ W2, fused alpha2 ----------------
__global__ __launch_bounds__(256) void gemm2_kernel(const float* __restrict__ elu1,
                                                    const float* __restrict__ W2,
                                                    const float* __restrict__ att_s,
                                                    const float* __restrict__ att_d,
                                                    unsigned short* __restrict__ h2b,
                                                    float* __restrict__ as2,
                                                    float* __restrict__ ad2, int n) {
    __shared__ float As[64][132];
    __shared__ float Bs[64][40];
    int tid = threadIdx.x;
    int r0 = blockIdx.x * 128;
    int cx = tid & 7, ry = tid >> 3;
    float sa[5], da[5];
#pragma unroll
    for (int j = 0; j < 5; ++j) {
        sa[j] = att_s[5 * cx + j];
        da[j] = att_d[5 * cx + j];
    }
    for (int t = tid; t < 640; t += 256) {
        int k = t / 10, cq = t % 10;
        *(float4*)&Bs[k][4 * cq] = *(const float4*)(W2 + (size_t)k * 40 + 4 * cq);
    }
    for (int t = tid; t < 2048; t += 256) {
        int row = t >> 4, kq = t & 15;
        int gr = r0 + row;
        float4 av = make_float4(0.f, 0.f, 0.f, 0.f);
        if (gr < n) av = *(const float4*)(elu1 + (size_t)gr * 64 + 4 * kq);
        As[4 * kq + 0][row] = av.x;
        As[4 * kq + 1][row] = av.y;
        As[4 * kq + 2][row] = av.z;
        As[4 * kq + 3][row] = av.w;
    }
    __syncthreads();
    float acc[4][5] = {{0.f}};
#pragma unroll 8
    for (int k = 0; k < 64; ++k) {
        float4 a = *(const float4*)&As[k][4 * ry];
        float ar[4] = {a.x, a.y, a.z, a.w};
        float br[5];
#pragma unroll
        for (int j = 0; j < 5; ++j) br[j] = Bs[k][5 * cx + j];
#pragma unroll
        for (int i = 0; i < 4; ++i)
#pragma unroll
            for (int j = 0; j < 5; ++j) acc[i][j] = fmaf(ar[i], br[j], acc[i][j]);
    }
#pragma unroll
    for (int i = 0; i < 4; ++i) {
        int gr = r0 + 4 * ry + i;
        float ps = 0.f, pd = 0.f;
#pragma unroll
        for (int j = 0; j < 5; ++j) {
            ps = fmaf(acc[i][j], sa[j], ps);
            pd = fmaf(acc[i][j], da[j], pd);
        }
        ps += __shfl_xor(ps, 1); pd += __shfl_xor(pd, 1);
        ps += __shfl_xor(ps, 2); pd += __shfl_xor(pd, 2);
        ps += __shfl_xor(ps, 4); pd += __shfl_xor(pd, 4);
        if (gr < n) {
#pragma unroll
            for (int j = 0; j < 5; ++j) h2b[(size_t)gr * 40 + 5 * cx + j] = bf16_of(acc[i][j]);
            if (cx == 0) {
                as2[gr] = ps;
                ad2[gr] = pd;
            }
        }
    }
}

// ---------------- Layer 2 aggregation (single-pass) + bias + log_softmax ----------------
__global__ __launch_bounds__(256) void agg2_kernel(const unsigned short* __restrict__ h2b,
                                                   const float* __restrict__ as2,
                                                   const float* __restrict__ ad2,
                                                   const float* __restrict__ b2,
                                                   const int* __restrict__ row_ptr,
                                                   const int* __restrict__ csr_src,
                                                   float* __restrict__ out, int n) {
    int lane = threadIdx.x & 63;
    int node = blockIdx.x * 4 + (threadIdx.x >> 6);
    if (node >= n) return;
    int start = row_ptr[node], end = row_ptr[node + 1];
    float adn = ad2[node];

    int q = lane >> 5, p = lane & 31;
    int pc = min(p, 19);
    const unsigned* h2u = (const unsigned*)h2b;  // row stride 20 uints (80B)
    f32x2 o = {0.f, 0.f};
    float den = 0.f;
    for (int base = start; base < end; base += 64) {
        int nloc = min(64, end - base);
        int eidx = base + lane;
        bool valid = eidx < end;
        int sAll = valid ? csr_src[eidx] : 0;
        float v = lrelu(as2[sAll] + adn);
        float w = valid ? __expf(v) : 0.f;
        den += w;
        int g = 0;
        for (; g + 8 <= nloc; g += 8) {
#pragma unroll
            for (int j = 0; j < 8; j += 2) {
                int idx = g + j + q;
                int sj = __shfl(sAll, idx);
                float wj = __shfl(w, idx);
                f32x2 w2 = {wj, wj};
                o = pk_fma(unpack_bf2v(h2u[(size_t)sj * 20 + pc]), w2, o);
            }
        }
        if (g < nloc) {
            int jmax = nloc - g;
            for (int j = 0; j < jmax; j += 2) {
                int idx = g + j + q;
                int sj = __shfl(sAll, idx);
                float wj = __shfl(w, idx);
                f32x2 w2 = {wj, wj};
                o = pk_fma(unpack_bf2v(h2u[(size_t)sj * 20 + pc]), w2, o);
            }
        }
    }
#pragma unroll
    for (int off = 1; off < 64; off <<= 1) den += __shfl_xor(den, off);
    float inv = 1.f / den;
    o.x += __shfl_xor(o.x, 32);
    o.y += __shfl_xor(o.y, 32);
    bool act = (lane < 32) && (p < 20);
    float v0 = -1e30f, v1 = -1e30f;
    if (act) {
        float2 bb = *(const float2*)(b2 + 2 * p);
        v0 = o.x * inv + bb.x;
        v1 = o.y * inv + bb.y;
    }
    float vm = fmaxf(v0, v1);
#pragma unroll
    for (int off = 1; off < 64; off <<= 1) vm = fmaxf(vm, __shfl_xor(vm, off));
    float ex = act ? (__expf(v0 - vm) + __expf(v1 - vm)) : 0.f;
#pragma unroll
    for (int off = 1; off < 64; off <<= 1) ex += __shfl_xor(ex, off);
    if (act) {
        float lg = __logf(ex);
        *(float2*)(out + (size_t)node * 40 + 2 * p) = make_float2(v0 - vm - lg, v1 - vm - lg);
    }
}

// ---------------- launch ----------------
extern "C" void kernel_launch(void* const* d_in, const int* in_sizes, int n_in,
                              void* d_out, int out_size, void* d_ws, size_t ws_size,
                              hipStream_t stream) {
    const float* x        = (const float*)d_in[0];
    const float* W1       = (const float*)d_in[1];
    const float* att_src1 = (const float*)d_in[2];
    const float* att_dst1 = (const float*)d_in[3];
    const float* b1       = (const float*)d_in[4];
    const float* W2       = (const float*)d_in[5];
    const float* att_src2 = (const float*)d_in[6];
    const float* att_dst2 = (const float*)d_in[7];
    const float* b2       = (const float*)d_in[8];
    const int*   ei       = (const int*)d_in[9];

    int n    = in_sizes[0] / 256;   // 100000
    int etot = in_sizes[9] / 2;     // 1700000
    const int* srcp = ei;
    const int* dstp = ei + etot;

    int npart = (n + 127) >> 7;           // 782
    int chunk = (etot + NBLK - 1) / NBLK; // ~6641

    char* ws = (char*)d_ws;
    size_t off = 0;
    unsigned short* h1b = (unsigned short*)(ws + off); off += (size_t)n * 64 * 2;
    unsigned short* h2b = (unsigned short*)(ws + off); off += (size_t)n * 40 * 2;
    unsigned short* W1t = (unsigned short*)(ws + off); off += (size_t)64 * 256 * 2;
    float* elu1 = (float*)(ws + off); off += (size_t)n * 64 * 4;
    float* as1  = (float*)(ws + off); off += (size_t)n * 8 * 4;
    float* ad1  = (float*)(ws + off); off += (size_t)n * 8 * 4;
    float* as2  = (float*)(ws + off); off += (size_t)n * 4;
    float* ad2  = (float*)(ws + off); off += (size_t)n * 4;
    int* row_ptr = (int*)(ws + off); off += (size_t)(n + 64) * 4;
    int* csr_src = (int*)(ws + off); off += (size_t)etot * 4;
    int* blk_cnt = (int*)(ws + off); off += (size_t)NBLK * npart * 4;
    int* blk_base= (int*)(ws + off); off += (size_t)NBLK * npart * 4;
    int* ptot    = (int*)(ws + off); off += (size_t)npart * 4;
    int* colbase = (int*)(ws + off); off += (size_t)(npart + 1) * 4;
    float* outp = (float*)d_out;

    // packed bucket list aliases elu1 (etot*4 = 6.8MB <= n*64*4 = 25.6MB);
    // elu1 is only written by agg1, after build_kernel completes (stream-ordered).
    int* eb = (int*)elu1;

    int g1 = (n + 63) / 64;      // 1563 gemm1 blocks (64 rows each)
    int nb4 = (n + 3) / 4;

    w1cvt_kernel<<<64, 256, 0, stream>>>(W1, W1t);
    fusedA_kernel<<<g1 + NBLK, 256, 0, stream>>>(x, W1t, att_src1, att_dst1, h1b, as1, ad1, n,
                                                 dstp, blk_cnt, etot, npart, chunk, g1);
    pscanA_kernel<<<npart, 256, 0, stream>>>(blk_cnt, blk_base, ptot, npart);
    pscanB_kernel<<<1, 1024, 0, stream>>>(ptot, colbase, npart, etot);
    pscatter_kernel<<<NBLK, 256, 0, stream>>>(srcp, dstp, blk_base, colbase, eb, etot, npart, chunk);
    build_kernel<<<npart, 256, 0, stream>>>(eb, colbase, row_ptr, csr_src, n, etot);
    agg1_kernel<<<nb4, 256, 0, stream>>>(h1b, as1, ad1, b1, row_ptr, csr_src, elu1, n);
    gemm2_kernel<<<(n + 127) / 128, 256, 0, stream>>>(elu1, W2, att_src2, att_dst2, h2b, as2, ad2, n);
    agg2_kernel<<<nb4, 256, 0, stream>>>(h2b, as2, ad2, b2, row_ptr, csr_src, outp, n);
}